// Round 1
// 231.085 us; speedup vs baseline: 1.1207x; 1.1207x over previous
//
#include <hip/hip_runtime.h>

typedef unsigned short u16;
typedef unsigned int   u32;

typedef __attribute__((ext_vector_type(8))) short short8;   // 8 bf16 (4 VGPRs)
typedef __attribute__((ext_vector_type(4))) float f32x4;    // MFMA acc

union Frag { u32 u[4]; short8 s; };

__device__ __forceinline__ u32 fbits(float f){ union{float f;u32 u;}x; x.f=f; return x.u; }
__device__ __forceinline__ float bitsf(u32 u){ union{u32 u;float f;}x; x.u=u; return x.f; }
__device__ __forceinline__ u32 pack_trunc(float a, float b){
    return __builtin_amdgcn_perm(fbits(b), fbits(a), 0x07060302u);
}
__device__ __forceinline__ u32 bf16_rne(float a){
    u32 u = fbits(a); return (u + 0x7FFFu + ((u >> 16) & 1u)) >> 16;
}
__device__ __forceinline__ u32 pack_rne(float a, float b){
    return bf16_rne(a) | (bf16_rne(b) << 16);
}
__device__ __forceinline__ float sigmoidf_(float x){
    return __builtin_amdgcn_rcpf(1.0f + __expf(-x));
}
__device__ __forceinline__ float tanhf_(float x){
    return 1.0f - 2.0f * __builtin_amdgcn_rcpf(__expf(2.0f * x) + 1.0f);
}

// Row-split design: 4 waves, wave w owns h rows 16w..16w+15 (full K=64, no
// partial exchange). h(t) lives in LDS as pre-packed bf16 hi/lo ping-pong
// buffers; the ds_read IS the MFMA B-fragment (zero read-side pack VALU).
// LDS total ~17.7 KB -> grid 1024 x 4 waves = 16 waves/CU (4/SIMD).
struct __align__(16) SharedMem {
    union {
        struct {                       // loop state: 13,312 B
            u16   hh[2][16][72];       // h hi-bf16, ping-pong [buf][seq][k], pad 64->72
            u16   hl[2][16][72];       // h lo-bf16
            float wih[768];            // Wih (192,4)
            float uw[4][64];           // per-wave u buffer [seq*4+c]
        } lp;
        struct {                       // tail: 11,524 B
            float wl[1152];
            float bl[16];
            float wcf[640];
            float bcf[20];
            float wcc[80];
            float bcc[20];
            float wcm[400];
            float bcm[20];
            float wfin[20];
            float bfin;
            float line[2][128];
            float pp[2][128];
        } tl;
    };
    float h[16 * 68];                  // final h (f32) for the tail, 4352 B
};

__global__ __launch_bounds__(256, 4)
void FRAPRQ_fused_kernel(
    const float* __restrict__ feat,       // (B,16)
    const float* __restrict__ hist,       // (B,64,24)
    const int*   __restrict__ relation,   // (8,7)
    const float* __restrict__ emb_phase,  // (2,4)
    const float* __restrict__ Wv,         // (4,1)
    const float* __restrict__ bv,         // (4)
    const float* __restrict__ Wh,         // (4,3)
    const float* __restrict__ bh,         // (4)
    const float* __restrict__ Wih,        // (192,4)
    const float* __restrict__ Whh,        // (192,64)
    const float* __restrict__ bih,        // (192)
    const float* __restrict__ bhh,        // (192)
    const float* __restrict__ Wl,         // (16,72)
    const float* __restrict__ bl,         // (16)
    const float* __restrict__ emb_const,  // (2,4)
    const float* __restrict__ Wcf,        // (20,32)
    const float* __restrict__ bcf,        // (20)
    const float* __restrict__ Wcc,        // (20,4)
    const float* __restrict__ bcc,        // (20)
    const float* __restrict__ Wcm,        // (20,20)
    const float* __restrict__ bcm,        // (20)
    const float* __restrict__ Wfin,      // (1,20)
    const float* __restrict__ bfin,      // (1)
    float* __restrict__ out)             // (B,8)
{
    __shared__ SharedMem sm;
    const int tid  = threadIdx.x;        // 0..255
    const int w    = tid >> 6;           // wave 0..3: owns h rows 16w..16w+15
    const int lane = tid & 63;
    const int sq   = lane & 15;          // MFMA column: local seq (2 b's x 8 lanes)
    const int q    = lane >> 4;          // MFMA quad
    const int b_base = blockIdx.x * 2;

    // ---- cooperative staging ----
    for (int i = tid; i < 768; i += 256) sm.lp.wih[i] = Wih[i];
    {   // zero both hi/lo ping-pong h buffers (h(-1) = 0); hh/hl are adjacent
        u32* z = (u32*)&sm.lp.hh[0][0][0];
        #pragma unroll 1
        for (int i = tid; i < 2304; i += 256) z[i] = 0u;
    }

    // ---- A-fragments: gate g3 (0=r,1=z,2=n) x K-chunk c; idx = 2*g3 + c ----
    // A row = sq within tile rows 64*g3 + 16*w .. +15; k = 32c + 8q + 0..7
    Frag ahi[6], alo[6];
    #pragma unroll
    for (int g3 = 0; g3 < 3; ++g3){
        #pragma unroll
        for (int c = 0; c < 2; ++c){
            const int idx = g3 * 2 + c;
            const float* wp = Whh + (64 * g3 + 16 * w + sq) * 64 + 32 * c + 8 * q;
            const float4 fA = *(const float4*)wp;
            const float4 fB = *(const float4*)(wp + 4);
            const float f[8] = {fA.x, fA.y, fA.z, fA.w, fB.x, fB.y, fB.z, fB.w};
            #pragma unroll
            for (int p = 0; p < 4; ++p){
                const u32 hi = pack_rne(f[2*p], f[2*p+1]);
                ahi[idx].u[p] = hi;
                const float l0 = f[2*p]   - bitsf((hi & 0xFFFFu) << 16);
                const float l1 = f[2*p+1] - bitsf(hi & 0xFFFF0000u);
                alo[idx].u[p] = pack_rne(l0, l1);
            }
        }
    }

    // ---- per-lane biases for OWNED rows j = 16w + 4q + r ----
    float bR[4], bZ[4], bNi[4], bNh[4];
    #pragma unroll
    for (int r = 0; r < 4; ++r){
        const int j = 16 * w + 4 * q + r;
        bR[r]  = bih[j]       + bhh[j];
        bZ[r]  = bih[64 + j]  + bhh[64 + j];
        bNi[r] = bih[128 + j];
        bNh[r] = bhh[128 + j];
    }

    // ---- u path: lane computes u[s=sq][c=q]; redundant per wave ----
    const int bs = b_base + (sq >> 3);
    const int ls = sq & 7;
    const float* hb = hist + (size_t)bs * 1536;
    const float wh0 = Wh[q*3+0], wh1 = Wh[q*3+1], wh2 = Wh[q*3+2], bhc = bh[q];
    float* uwp = &sm.lp.uw[w][0];
    {
        const float y0 = hb[ls], y1 = hb[ls + 8], y2 = hb[ls + 16];
        uwp[sq * 4 + q] = sigmoidf_(fmaf(wh0, y0, fmaf(wh1, y1, fmaf(wh2, y2, bhc))));
    }
    float x0 = hb[24 + ls], x1 = hb[24 + ls + 8], x2 = hb[24 + ls + 16];

    float hreg[4] = {0.f, 0.f, 0.f, 0.f};

    __syncthreads();   // staging + h init visible

    #pragma unroll 1
    for (int t = 0; t < 64; ++t){
        const int rb = t & 1;          // read h(t-1) from buf rb, write h(t) to rb^1

        // B fragments: direct b128 reads of pre-packed bf16 (no pack VALU)
        const short8 bh0 = *(const short8*)&sm.lp.hh[rb][sq][8 * q];
        const short8 bl0 = *(const short8*)&sm.lp.hl[rb][sq][8 * q];
        const short8 bh1 = *(const short8*)&sm.lp.hh[rb][sq][32 + 8 * q];
        const short8 bl1 = *(const short8*)&sm.lp.hl[rb][sq][32 + 8 * q];

        // acc init: r/z = gi (u4 . Wih + biases), n = bhh_n; giN kept separate
        const float4 u4 = *(const float4*)&uwp[sq * 4];
        f32x4 aR, aZ, aN;
        float giN[4];
        #pragma unroll
        for (int r = 0; r < 4; ++r){
            const int j = 16 * w + 4 * q + r;
            const float4 wr = *(const float4*)&sm.lp.wih[j * 4];
            const float4 wz = *(const float4*)&sm.lp.wih[(64 + j) * 4];
            const float4 wn = *(const float4*)&sm.lp.wih[(128 + j) * 4];
            aR[r]  = fmaf(wr.x,u4.x, fmaf(wr.y,u4.y, fmaf(wr.z,u4.z, fmaf(wr.w,u4.w, bR[r]))));
            aZ[r]  = fmaf(wz.x,u4.x, fmaf(wz.y,u4.y, fmaf(wz.z,u4.z, fmaf(wz.w,u4.w, bZ[r]))));
            giN[r] = fmaf(wn.x,u4.x, fmaf(wn.y,u4.y, fmaf(wn.z,u4.z, fmaf(wn.w,u4.w, bNi[r]))));
            aN[r]  = bNh[r];
        }

        // 18 MFMAs: 3 gates x 2 K-chunks x {hi.hi, hi.lo, lo.hi}; full K, no exchange
        #define MM3(acc, i, BH, BL) \
            acc = __builtin_amdgcn_mfma_f32_16x16x32_bf16(ahi[i].s, BH, acc, 0, 0, 0); \
            acc = __builtin_amdgcn_mfma_f32_16x16x32_bf16(ahi[i].s, BL, acc, 0, 0, 0); \
            acc = __builtin_amdgcn_mfma_f32_16x16x32_bf16(alo[i].s, BH, acc, 0, 0, 0);
        MM3(aR, 0, bh0, bl0)
        MM3(aZ, 2, bh0, bl0)
        MM3(aN, 4, bh0, bl0)
        MM3(aR, 1, bh1, bl1)
        MM3(aZ, 3, bh1, bl1)
        MM3(aN, 5, bh1, bl1)
        #undef MM3

        // gates + h update (acc is COMPLETE: no partner partials)
        float hn4[4];
        #pragma unroll
        for (int r = 0; r < 4; ++r){
            const float rr   = sigmoidf_(aR[r]);
            const float zz   = sigmoidf_(aZ[r]);
            const float cand = tanhf_(fmaf(rr, aN[r], giN[r]));
            const float hn   = fmaf(zz, hreg[r] - cand, cand);
            hreg[r] = hn;
            hn4[r] = hn;
        }

        // pack h(t) -> bf16 hi/lo ONCE (write side), ds_write_b64 each
        {
            const u32 hi0 = pack_trunc(hn4[0], hn4[1]);
            const u32 hi1 = pack_trunc(hn4[2], hn4[3]);
            const float l0 = hn4[0] - bitsf((hi0 & 0xFFFFu) << 16);
            const float l1 = hn4[1] - bitsf(hi0 & 0xFFFF0000u);
            const float l2 = hn4[2] - bitsf((hi1 & 0xFFFFu) << 16);
            const float l3 = hn4[3] - bitsf(hi1 & 0xFFFF0000u);
            const u32 lo0 = pack_trunc(l0, l1);
            const u32 lo1 = pack_trunc(l2, l3);
            const int wb = rb ^ 1;
            *(uint2*)&sm.lp.hh[wb][sq][16 * w + 4 * q] = make_uint2(hi0, hi1);
            *(uint2*)&sm.lp.hl[wb][sq][16 * w + 4 * q] = make_uint2(lo0, lo1);
        }

        // u(t+1); prefetch x(t+2)  (wave-private buffer: no barrier needed)
        uwp[sq * 4 + q] = sigmoidf_(fmaf(wh0, x0, fmaf(wh1, x1, fmaf(wh2, x2, bhc))));
        const int tn = (t + 2 < 64) ? (t + 2) : 63;
        x0 = hb[tn*24 + ls]; x1 = hb[tn*24 + ls + 8]; x2 = hb[tn*24 + ls + 16];

        __syncthreads();   // single barrier per step (hi/lo ping-pong)
    }

    // ---- final h (f32) for the tail, straight from registers ----
    {
        const float4 hv = make_float4(hreg[0], hreg[1], hreg[2], hreg[3]);
        *(float4*)&sm.h[sq * 68 + 16 * w + 4 * q] = hv;
    }

    // ---- stage tail weights into the (dead) loop region ----
    for (int i = tid; i < 1152; i += 256) sm.tl.wl[i]  = Wl[i];
    for (int i = tid; i <  640; i += 256) sm.tl.wcf[i] = Wcf[i];
    for (int i = tid; i <  400; i += 256) sm.tl.wcm[i] = Wcm[i];
    if (tid < 80) sm.tl.wcc[tid] = Wcc[tid];
    if (tid < 20){
        sm.tl.bcf[tid]  = bcf[tid];
        sm.tl.bcc[tid]  = bcc[tid];
        sm.tl.bcm[tid]  = bcm[tid];
        sm.tl.wfin[tid] = Wfin[tid];
    }
    if (tid < 16) sm.tl.bl[tid] = bl[tid];
    if (tid == 0) sm.tl.bfin = bfin[0];
    __syncthreads();   // h writes + tail weights visible

    // ---- tail Phase A: wave (g = w&1) x (half = w>>1); 8 outputs/wave ----
    {
        const int g    = w & 1;
        const int half = w >> 1;
        const int b    = b_base + g;
        const int l = lane >> 3, o = lane & 7;
        float fv[8];
        const float vraw = feat[b * 16 + 8 + l];
        const int   bit  = ((int)feat[b * 16 + l]) & 1;
        #pragma unroll
        for (int c = 0; c < 4; ++c){
            fv[c]     = sigmoidf_(fmaf(vraw, Wv[c], bv[c]));
            fv[4 + c] = sigmoidf_(emb_phase[bit * 4 + c]);
        }
        const float* hrow = &sm.h[(g * 8 + l) * 68];
        const int oo = o + half * 8;
        float acc = sm.tl.bl[oo];
        #pragma unroll
        for (int f = 0; f < 8; ++f) acc = fmaf(fv[f], sm.tl.wl[oo * 72 + f], acc);
        for (int k = 0; k < 64; ++k) acc = fmaf(hrow[k], sm.tl.wl[oo * 72 + 8 + k], acc);
        sm.tl.line[g][l * 16 + oo] = fmaxf(acc, 0.0f);
    }
    __syncthreads();   // line written by wave pairs {g, g+2}

    // ---- Phases B/C/out: waves 0,1 only (wave-private from here) ----
    if (w < 2){
        const int g = w;
        const int b = b_base + g;
        // Phase B
        {
            const int p = lane >> 3, o = lane & 7;
            const int l0 = (0x64204501u >> (p * 4)) & 15;
            const int l1 = (0x75316723u >> (p * 4)) & 15;
            sm.tl.pp[g][p * 16 + o]     = sm.tl.line[g][l0 * 16 + o]     + sm.tl.line[g][l1 * 16 + o];
            sm.tl.pp[g][p * 16 + o + 8] = sm.tl.line[g][l0 * 16 + o + 8] + sm.tl.line[g][l1 * 16 + o + 8];
        }
        __builtin_amdgcn_wave_barrier();
        // Phase C
        if (lane < 56){
            const int p  = lane / 7;
            const int qi = lane - p * 7;
            const int jl = qi + (qi >= p ? 1 : 0);
            float fmv[32];
            #pragma unroll
            for (int f = 0; f < 16; ++f){
                fmv[f]      = sm.tl.pp[g][p  * 16 + f];
                fmv[16 + f] = sm.tl.pp[g][jl * 16 + f];
            }
            const int rel = relation[p * 7 + qi] & 1;
            float ce[4];
            #pragma unroll
            for (int c = 0; c < 4; ++c) ce[c] = emb_const[rel * 4 + c];
            float m[20];
            for (int o = 0; o < 20; ++o){
                float xf = sm.tl.bcf[o];
                #pragma unroll
                for (int f = 0; f < 32; ++f) xf = fmaf(fmv[f], sm.tl.wcf[o * 32 + f], xf);
                float yc = sm.tl.bcc[o];
                #pragma unroll
                for (int c = 0; c < 4; ++c) yc = fmaf(ce[c], sm.tl.wcc[o * 4 + c], yc);
                m[o] = fmaxf(xf, 0.0f) * fmaxf(yc, 0.0f);
            }
            float fin = sm.tl.bfin;
            for (int o = 0; o < 20; ++o){
                float zz = sm.tl.bcm[o];
                #pragma unroll
                for (int c = 0; c < 20; ++c) zz = fmaf(m[c], sm.tl.wcm[o * 20 + c], zz);
                fin = fmaf(fmaxf(zz, 0.0f), sm.tl.wfin[o], fin);
            }
            sm.tl.line[g][lane] = fin;   // line dead after Phase B
        }
        __builtin_amdgcn_wave_barrier();
        if (lane < 8){
            float acc = 0.0f;
            #pragma unroll
            for (int qq = 0; qq < 7; ++qq) acc += sm.tl.line[g][lane * 7 + qq];
            out[b * 8 + lane] = acc;
        }
    }
}

extern "C" void kernel_launch(void* const* d_in, const int* in_sizes, int n_in,
                              void* d_out, int out_size, void* d_ws, size_t ws_size,
                              hipStream_t stream) {
    (void)n_in; (void)d_ws; (void)ws_size; (void)out_size;
    const float* feat      = (const float*)d_in[0];
    const float* hist      = (const float*)d_in[1];
    const int*   relation  = (const int*)d_in[2];
    const float* emb_phase = (const float*)d_in[3];
    const float* Wv        = (const float*)d_in[4];
    const float* bv        = (const float*)d_in[5];
    const float* Wh        = (const float*)d_in[6];
    const float* bh        = (const float*)d_in[7];
    const float* Wih       = (const float*)d_in[8];
    const float* Whh       = (const float*)d_in[9];
    const float* bih       = (const float*)d_in[10];
    const float* bhh       = (const float*)d_in[11];
    const float* Wl        = (const float*)d_in[12];
    const float* bl        = (const float*)d_in[13];
    const float* emb_const = (const float*)d_in[14];
    const float* Wcf       = (const float*)d_in[15];
    const float* bcf       = (const float*)d_in[16];
    const float* Wcc       = (const float*)d_in[17];
    const float* bcc       = (const float*)d_in[18];
    const float* Wcm       = (const float*)d_in[19];
    const float* bcm       = (const float*)d_in[20];
    const float* Wfin      = (const float*)d_in[21];
    const float* bfin      = (const float*)d_in[22];
    float* out = (float*)d_out;

    const int B = in_sizes[0] / 16;     // 2048
    const int nblocks = B / 2;          // 1024 blocks x 4 waves: row-split GRU
    FRAPRQ_fused_kernel<<<nblocks, 256, 0, stream>>>(
        feat, hist, relation, emb_phase, Wv, bv, Wh, bh, Wih, Whh, bih, bhh,
        Wl, bl, emb_const, Wcf, bcf, Wcc, bcc, Wcm, bcm, Wfin, bfin, out);
}